// Round 1
// baseline (169.390 us; speedup 1.0000x reference)
//
#include <hip/hip_runtime.h>
#include <hip/hip_bf16.h>

// Problem constants
constexpr int NQ   = 4096;   // spatial tokens (H*W)
constexpr int NKV  = 4112;   // spatial + 16 memory tokens
constexpr int NP   = 4160;   // padded rows (65 * 64), pad is zeroed
constexpr int CDIM = 128;
constexpr float QSC = 0.17677669529663687f * 1.4426950408889634f; // DH^-0.5 * log2(e)

typedef __attribute__((ext_vector_type(8)))  short bf16x8;
typedef __attribute__((ext_vector_type(4)))  float f32x4;
typedef __attribute__((ext_vector_type(16))) float f32x16;

static __device__ __forceinline__ unsigned short bfbits(float f) {
  __hip_bfloat16 h = __float2bfloat16(f);
  return *reinterpret_cast<unsigned short*>(&h);
}
static __device__ __forceinline__ unsigned pk2(float a, float b) {
  return (unsigned)bfbits(a) | ((unsigned)bfbits(b) << 16);
}

// ---------------- Kernel 1: QKV projection (+ w_out cast) ----------------
// grid (65, 4 batches), block 256.  Writes:
//   Qt[bh][n][d] (bf16, pre-scaled by QSC), Kt[bh][n][d], Vt[bh][d][n]
__global__ __launch_bounds__(256) void k1_qkv(
    const float* __restrict__ x, const float* __restrict__ memry,
    const float* __restrict__ wqkv, const float* __restrict__ wout,
    __hip_bfloat16* __restrict__ Qt, __hip_bfloat16* __restrict__ Kt,
    __hip_bfloat16* __restrict__ Vt, __hip_bfloat16* __restrict__ Wb) {
  __shared__ __align__(16) __hip_bfloat16 xt[64][136];  // [n-local][c], +8 pad
  const int b  = blockIdx.y;
  const int nb = blockIdx.x * 64;
  const int t  = threadIdx.x;
  const int wv = t >> 6, ln = t & 63;

  if (blockIdx.x == 0 && b == 0) {
    for (int i = t; i < CDIM * CDIM; i += 256) Wb[i] = __float2bfloat16(wout[i]);
  }

  { // stage x_ext tile (transposed, bf16)
    const int n = nb + ln;
    #pragma unroll
    for (int i = 0; i < 16; ++i) {
      const int c = wv * 32 + 2 * i;
      float v0 = 0.f, v1 = 0.f;
      if (n < NQ)        { v0 = x[((size_t)b * CDIM + c) * NQ + n];
                           v1 = x[((size_t)b * CDIM + c + 1) * NQ + n]; }
      else if (n < NKV)  { v0 = memry[c * 16 + (n - NQ)];
                           v1 = memry[(c + 1) * 16 + (n - NQ)]; }
      *reinterpret_cast<unsigned*>(&xt[ln][c]) =
          (unsigned)bfbits(v0) | ((unsigned)bfbits(v1) << 16);
    }
  }
  __syncthreads();

  const int li = ln & 15, g = ln >> 4;
  bf16x8 xa[4][4];
  #pragma unroll
  for (int nt = 0; nt < 4; ++nt)
    #pragma unroll
    for (int k = 0; k < 4; ++k)
      xa[nt][k] = *reinterpret_cast<const bf16x8*>(&xt[nt * 16 + li][k * 32 + 8 * g]);

  #pragma unroll
  for (int oi = 0; oi < 6; ++oi) {
    const int ot = wv * 6 + oi;                 // 24 o-tiles of 16: 0-7 Q, 8-15 K, 16-23 V
    bf16x8 wf[4];
    #pragma unroll
    for (int k = 0; k < 4; ++k) {
      const float* wp = &wqkv[(size_t)(ot * 16 + li) * CDIM + k * 32 + 8 * g];
      const float4 f0 = *reinterpret_cast<const float4*>(wp);
      const float4 f1 = *reinterpret_cast<const float4*>(wp + 4);
      bf16x8 wc;
      wc[0] = (short)bfbits(f0.x); wc[1] = (short)bfbits(f0.y);
      wc[2] = (short)bfbits(f0.z); wc[3] = (short)bfbits(f0.w);
      wc[4] = (short)bfbits(f1.x); wc[5] = (short)bfbits(f1.y);
      wc[6] = (short)bfbits(f1.z); wc[7] = (short)bfbits(f1.w);
      wf[k] = wc;
    }
    #pragma unroll
    for (int nt = 0; nt < 4; ++nt) {
      f32x4 a; a[0] = a[1] = a[2] = a[3] = 0.f;
      if (ot < 16) {
        // D[row=n][col=o]  (A = x-tile, B = W^T)
        #pragma unroll
        for (int k = 0; k < 4; ++k)
          a = __builtin_amdgcn_mfma_f32_16x16x32_bf16(xa[nt][k], wf[k], a, 0, 0, 0);
        const int o = ot * 16 + li;
        const int h = (o >> 5) & 3, d = o & 31;
        if (ot < 8) {
          #pragma unroll
          for (int r = 0; r < 4; ++r) {
            const int n = nb + nt * 16 + 4 * g + r;
            Qt[((size_t)(b * 4 + h) * NP + n) * 32 + d] = __float2bfloat16(a[r] * QSC);
          }
        } else {
          #pragma unroll
          for (int r = 0; r < 4; ++r) {
            const int n = nb + nt * 16 + 4 * g + r;
            Kt[((size_t)(b * 4 + h) * NP + n) * 32 + d] = __float2bfloat16(a[r]);
          }
        }
      } else {
        // D[row=o][col=n]  (A = W, B = x-tile)
        #pragma unroll
        for (int k = 0; k < 4; ++k)
          a = __builtin_amdgcn_mfma_f32_16x16x32_bf16(wf[k], xa[nt][k], a, 0, 0, 0);
        #pragma unroll
        for (int r = 0; r < 4; ++r) {
          const int o = ot * 16 + 4 * g + r;
          const int h = (o >> 5) & 3, d = o & 31;
          const int n = nb + nt * 16 + li;
          Vt[((size_t)(b * 4 + h) * 32 + d) * NP + n] = __float2bfloat16(a[r]);
        }
      }
    }
  }
}

// ---------------- Kernel 2: flash attention (swapped operands) ----------------
// grid (32 q-blocks, 16 bh), block 256 = 4 waves, 32 q per wave.
__global__ __launch_bounds__(256) void k2_attn(
    const __hip_bfloat16* __restrict__ Qt, const __hip_bfloat16* __restrict__ Kt,
    const __hip_bfloat16* __restrict__ Vt, __hip_bfloat16* __restrict__ att) {
  __shared__ float olds[4][32][33];
  const int bh = blockIdx.y;
  const int wv = threadIdx.x >> 6, lane = threadIdx.x & 63;
  const int lq = lane & 31, hi = lane >> 5;
  const int qb = blockIdx.x * 128 + wv * 32;

  const bf16x8 qf0 = *reinterpret_cast<const bf16x8*>(
      Qt + ((size_t)bh * NP + qb + lq) * 32 + 8 * hi);
  const bf16x8 qf1 = *reinterpret_cast<const bf16x8*>(
      Qt + ((size_t)bh * NP + qb + lq) * 32 + 16 + 8 * hi);
  const __hip_bfloat16* Vrow = Vt + ((size_t)bh * 32 + lq) * NP;

  f32x16 accv, z;
  #pragma unroll
  for (int i = 0; i < 16; ++i) { accv[i] = 0.f; z[i] = 0.f; }
  float m = -1e30f, lsum = 0.f;

  for (int kb = 0; kb < NKV; kb += 32) {
    const __hip_bfloat16* Krow = Kt + ((size_t)bh * NP + kb + lq) * 32 + 8 * hi;
    const bf16x8 kf0 = *reinterpret_cast<const bf16x8*>(Krow);
    const bf16x8 kf1 = *reinterpret_cast<const bf16x8*>(Krow + 16);
    // S^T[key][q]
    f32x16 s = __builtin_amdgcn_mfma_f32_32x32x16_bf16(kf0, qf0, z, 0, 0, 0);
    s = __builtin_amdgcn_mfma_f32_32x32x16_bf16(kf1, qf1, s, 0, 0, 0);

    if (kb + 32 > NKV) {  // tail mask
      #pragma unroll
      for (int r = 0; r < 16; ++r) {
        const int key = kb + (r & 3) + 8 * (r >> 2) + 4 * hi;
        if (key >= NKV) s[r] = -1e30f;
      }
    }
    float tm = s[0];
    #pragma unroll
    for (int r = 1; r < 16; ++r) tm = fmaxf(tm, s[r]);
    tm = fmaxf(tm, __shfl_xor(tm, 32, 64));
    const float mnew = fmaxf(m, tm);
    const float sc = __builtin_amdgcn_exp2f(m - mnew);
    float p[16], ps = 0.f;
    #pragma unroll
    for (int r = 0; r < 16; ++r) { p[r] = __builtin_amdgcn_exp2f(s[r] - mnew); ps += p[r]; }
    ps += __shfl_xor(ps, 32, 64);
    lsum = lsum * sc + ps;
    m = mnew;
    #pragma unroll
    for (int i = 0; i < 16; ++i) accv[i] *= sc;

    // assemble P as B-fragments: lane needs P[q=lq][j = 8*hi + j'] (+16 for 2nd frag)
    const unsigned A0 = pk2(p[0], p[1]),  A1 = pk2(p[2], p[3]);    // keys 4hi+0..3
    const unsigned B0 = pk2(p[4], p[5]),  B1 = pk2(p[6], p[7]);    // keys 8+4hi+0..3
    const unsigned C0 = pk2(p[8], p[9]),  C1 = pk2(p[10], p[11]);  // keys 16+4hi+0..3
    const unsigned D0 = pk2(p[12], p[13]), D1 = pk2(p[14], p[15]); // keys 24+4hi+0..3
    const unsigned x0 = __shfl_xor(hi ? A0 : B0, 32, 64);
    const unsigned x1 = __shfl_xor(hi ? A1 : B1, 32, 64);
    const unsigned y0 = __shfl_xor(hi ? C0 : D0, 32, 64);
    const unsigned y1 = __shfl_xor(hi ? C1 : D1, 32, 64);
    union UU { unsigned u[4]; bf16x8 v; };
    UU u1, u2;
    u1.u[0] = hi ? x0 : A0; u1.u[1] = hi ? x1 : A1;
    u1.u[2] = hi ? B0 : x0; u1.u[3] = hi ? B1 : x1;
    u2.u[0] = hi ? y0 : C0; u2.u[1] = hi ? y1 : C1;
    u2.u[2] = hi ? D0 : y0; u2.u[3] = hi ? D1 : y1;

    const bf16x8 vf0 = *reinterpret_cast<const bf16x8*>(Vrow + kb + 8 * hi);
    const bf16x8 vf1 = *reinterpret_cast<const bf16x8*>(Vrow + kb + 16 + 8 * hi);
    accv = __builtin_amdgcn_mfma_f32_32x32x16_bf16(vf0, u1.v, accv, 0, 0, 0);
    accv = __builtin_amdgcn_mfma_f32_32x32x16_bf16(vf1, u2.v, accv, 0, 0, 0);
  }

  const float inv = 1.f / lsum;
  #pragma unroll
  for (int r = 0; r < 16; ++r)
    olds[wv][lq][(r & 3) + 8 * (r >> 2) + 4 * hi] = accv[r] * inv;
  __syncthreads();

  const int b = bh >> 2, h = bh & 3;
  __hip_bfloat16* dst = att + ((size_t)b * NQ + qb + lq) * CDIM + h * 32 + hi * 16;
  unsigned wbuf[8];
  #pragma unroll
  for (int i = 0; i < 8; ++i)
    wbuf[i] = pk2(olds[wv][lq][hi * 16 + 2 * i], olds[wv][lq][hi * 16 + 2 * i + 1]);
  *reinterpret_cast<uint4*>(dst)     = make_uint4(wbuf[0], wbuf[1], wbuf[2], wbuf[3]);
  *reinterpret_cast<uint4*>(dst + 8) = make_uint4(wbuf[4], wbuf[5], wbuf[6], wbuf[7]);
}

// ---------------- Kernel 3: output projection ----------------
// grid (64 n-tiles, 4 batches), block 256.  out[b][o][n] = W·att + b
__global__ __launch_bounds__(256) void k3_proj(
    const __hip_bfloat16* __restrict__ att, const __hip_bfloat16* __restrict__ Wb,
    const float* __restrict__ bout, float* __restrict__ out) {
  const int b = blockIdx.y, nb = blockIdx.x * 64;
  const int wv = threadIdx.x >> 6, lane = threadIdx.x & 63;
  const int li = lane & 15, g = lane >> 4;

  bf16x8 wf[2][4];
  float bo[2][4];
  #pragma unroll
  for (int tt = 0; tt < 2; ++tt) {
    const int ot = 2 * wv + tt;
    #pragma unroll
    for (int k = 0; k < 4; ++k)
      wf[tt][k] = *reinterpret_cast<const bf16x8*>(
          &Wb[(size_t)(ot * 16 + li) * CDIM + k * 32 + 8 * g]);
    #pragma unroll
    for (int r = 0; r < 4; ++r) bo[tt][r] = bout[ot * 16 + 4 * g + r];
  }
  #pragma unroll
  for (int nt = 0; nt < 4; ++nt) {
    bf16x8 bfr[4];
    #pragma unroll
    for (int k = 0; k < 4; ++k)
      bfr[k] = *reinterpret_cast<const bf16x8*>(
          &att[((size_t)b * NQ + nb + nt * 16 + li) * CDIM + k * 32 + 8 * g]);
    #pragma unroll
    for (int tt = 0; tt < 2; ++tt) {
      f32x4 a; a[0] = a[1] = a[2] = a[3] = 0.f;
      #pragma unroll
      for (int k = 0; k < 4; ++k)
        a = __builtin_amdgcn_mfma_f32_16x16x32_bf16(wf[tt][k], bfr[k], a, 0, 0, 0);
      const int ot = 2 * wv + tt;
      #pragma unroll
      for (int r = 0; r < 4; ++r)
        out[((size_t)b * CDIM + ot * 16 + 4 * g + r) * NQ + nb + nt * 16 + li] =
            a[r] + bo[tt][r];
    }
  }
}

extern "C" void kernel_launch(void* const* d_in, const int* in_sizes, int n_in,
                              void* d_out, int out_size, void* d_ws, size_t ws_size,
                              hipStream_t stream) {
  const float* x    = (const float*)d_in[0];
  const float* memp = (const float*)d_in[1];
  const float* wqkv = (const float*)d_in[2];
  const float* wout = (const float*)d_in[3];
  const float* bout = (const float*)d_in[4];
  float* out = (float*)d_out;

  char* ws = (char*)d_ws;
  const size_t SZ = (size_t)16 * NP * 32 * 2;          // one of Qt/Kt/Vt
  __hip_bfloat16* Qt  = (__hip_bfloat16*)(ws);
  __hip_bfloat16* Kt  = (__hip_bfloat16*)(ws + SZ);
  __hip_bfloat16* Vt  = (__hip_bfloat16*)(ws + 2 * SZ);
  __hip_bfloat16* att = (__hip_bfloat16*)(ws + 3 * SZ);
  __hip_bfloat16* Wb  = (__hip_bfloat16*)(ws + 3 * SZ + (size_t)4 * NQ * CDIM * 2);

  hipLaunchKernelGGL(k1_qkv, dim3(65, 4), dim3(256), 0, stream,
                     x, memp, wqkv, wout, Qt, Kt, Vt, Wb);
  hipLaunchKernelGGL(k2_attn, dim3(32, 16), dim3(256), 0, stream, Qt, Kt, Vt, att);
  hipLaunchKernelGGL(k3_proj, dim3(64, 4), dim3(256), 0, stream, att, Wb, bout, out);
}